// Round 4
// baseline (210.059 us; speedup 1.0000x reference)
//
#include <hip/hip_runtime.h>

// MultipleKmeans: T=16384 frames, E=1024, M=8 models, K=512 clusters.
// Round 8: theory locked from R4-R7 invariance: k_dist is L3-BW-bound on
// B-panel re-reads (512 blocks x 1MB = 512MB at ~7TB/s ~= 82us; per-model
// XCD-L2 residency does NOT hold). Two changes:
//  1. FPB 32->64: each wave keeps its 64-col slice, covers BOTH 32-row
//     tiles (acc 2x2, two ds_reads/step) -> ~256 blocks x 1MB = 256MB B
//     traffic (halved). launch_bounds(512,2), 1 block/CU.
//  2. Resolution split OUT of k_dist into dense k_resolve: k_dist parks
//     candidate lists (cnt + ids) in out scratch cols [0,33) (disjoint
//     from B panels at cols [512,1024) of rows 0..4095); k_resolve does
//     fp64 recheck + row writes for ALL frames; k_gather removed.
//
// ws layout (<=100416 B):
//   [     0, 32768): double csq64[M*K]
//   [ 32768, 34816): int    hist[64][8]
//   [ 34816, 34880): int    offs[9]
//   [ 34880,100416): int    order[T]

#define T_FRAMES 16384
#define E_DIM    1024
#define M_MODELS 8
#define K_CLUST  512

#define FPB 64     // frames per k_dist block
#define NCH 8      // K chunks of 128

typedef __bf16 bf16x8 __attribute__((ext_vector_type(8)));
typedef float  floatx16 __attribute__((ext_vector_type(16)));

__device__ __forceinline__ bf16x8 cvt8(const float4 a, const float4 b) {
  bf16x8 h;
  h[0] = (__bf16)a.x; h[1] = (__bf16)a.y; h[2] = (__bf16)a.z; h[3] = (__bf16)a.w;
  h[4] = (__bf16)b.x; h[5] = (__bf16)b.y; h[6] = (__bf16)b.z; h[7] = (__bf16)b.w;
  return h;
}

// ------- K0: cent fp32 -> swizzled bf16 in d_out high halves + csq64 -------
__global__ __launch_bounds__(256) void k_cvt(const float* __restrict__ cent,
                                             float* __restrict__ out,
                                             double* __restrict__ csq64) {
  const int b = blockIdx.x;              // 512 blocks
  const int m = b >> 6;
  const int cg = (b >> 2) & 15;
  const int q = b & 3;
  const int tid = threadIdx.x;
  const int ci = tid & 31;
  const int t8 = tid >> 5;               // 0..7
  const int gk0 = q * 32 + t8 * 4;
  const int B32 = (m * 16 + cg) * 32;
  const float* src = cent + ((size_t)(m * K_CLUST + cg * 32 + ci)) * E_DIM;
  double ss = 0.0;
#pragma unroll
  for (int j = 0; j < 4; ++j) {
    const int gk = gk0 + j;
    const float4 a = *(const float4*)(src + gk * 8);
    const float4 bb = *(const float4*)(src + gk * 8 + 4);
    ss += (double)a.x * a.x + (double)a.y * a.y + (double)a.z * a.z +
          (double)a.w * a.w + (double)bb.x * bb.x + (double)bb.y * bb.y +
          (double)bb.z * bb.z + (double)bb.w * bb.w;
    const size_t foff = (size_t)(B32 + (gk >> 2)) * 1024 + 512 +
                        ((gk & 3) * 32 + ci) * 4;
    *(bf16x8*)(out + foff) = cvt8(a, bb);
  }
  __shared__ double csq_l[32][8];
  csq_l[ci][t8] = ss;
  __syncthreads();
  if (tid < 32) {
    double s = 0.0;
#pragma unroll
    for (int t = 0; t < 8; ++t) s += csq_l[tid][t];
    atomicAdd(&csq64[m * K_CLUST + cg * 32 + tid], s);
  }
}

// ---------------- K1: per-block model histogram (+ csq64 zeroing) ----------
__global__ __launch_bounds__(256) void k_hist(const int* __restrict__ midx,
                                              int* __restrict__ hist,
                                              double* __restrict__ csq64) {
  __shared__ int h[M_MODELS * 33];
  const int tid = threadIdx.x;
  if (tid < 64) csq64[blockIdx.x * 64 + tid] = 0.0;   // 64 blocks x 64 = 4096
  for (int i = tid; i < M_MODELS * 33; i += 256) h[i] = 0;
  __syncthreads();
  const int m = midx[blockIdx.x * 256 + tid];
  atomicAdd(&h[m * 33 + (tid & 31)], 1);
  __syncthreads();
  if (tid < M_MODELS) {
    int s = 0;
    for (int j = 0; j < 32; ++j) s += h[tid * 33 + j];
    hist[blockIdx.x * M_MODELS + tid] = s;
  }
}

// ---------------- K2: scatter frames into per-model buckets ----------------
__global__ __launch_bounds__(256) void k_scatter(const int* __restrict__ midx,
                                                 const int* __restrict__ hist,
                                                 int* __restrict__ order,
                                                 int* __restrict__ offs) {
  __shared__ int h2[64 * M_MODELS];
  __shared__ int cur[M_MODELS];
  const int tid = threadIdx.x;
  h2[tid] = hist[tid];
  h2[tid + 256] = hist[tid + 256];
  __syncthreads();
  if (tid < M_MODELS) {
    int tot_before = 0;
    for (int mp = 0; mp < tid; ++mp)
      for (int b = 0; b < 64; ++b) tot_before += h2[b * M_MODELS + mp];
    int prior = 0;
    for (int b = 0; b < (int)blockIdx.x; ++b) prior += h2[b * M_MODELS + tid];
    cur[tid] = tot_before + prior;
  }
  if (blockIdx.x == 0 && tid <= M_MODELS) {
    int o = 0;
    for (int mp = 0; mp < tid; ++mp)
      for (int b = 0; b < 64; ++b) o += h2[b * M_MODELS + mp];
    offs[tid] = o;
  }
  __syncthreads();
  const int f = blockIdx.x * 256 + tid;
  const int pos = atomicAdd(&cur[midx[f]], 1);
  order[pos] = f;
}

// ---------------- K3: fused scores + argmin -> candidate scratch -----------
// Block: 8 waves (512 thr), tile = 64 frames x 512 cols; wave w -> cols
// [w*64, w*64+64), BOTH 32-row tiles. acc: 2x2 32x32 tiles = 64 regs/wave.
// A: LDS chunks of 128 k, double-buffered (32 KB). B: swizzled bf16
// (d_out rows 0..4095 high halves), depth-4 ring. Per-block B = 1 MB read
// ONCE -> ~256 blocks = 256 MB total (halved vs FPB=32).
// Epilogue: candidate lists (cnt at col 0, ids at cols 1..n) parked in out
// scratch; k_resolve finishes.
__global__ __launch_bounds__(512, 2) void k_dist(const float* __restrict__ emb,
                                                 const float* __restrict__ cent,
                                                 const double* __restrict__ csq64,
                                                 const int* __restrict__ order,
                                                 const int* __restrict__ offs,
                                                 float* __restrict__ out) {
  const int m = blockIdx.x;
  const int o0 = offs[m];
  const int cnt = offs[m + 1] - o0;
  const int start = blockIdx.y * FPB;
  if (start >= cnt) return;
  const int nvalid = min(FPB, cnt - start);

  __shared__ __align__(16) __bf16 A_l[2 * 16 * FPB * 8];  // 32 KB
  __shared__ int rows_l[FPB];
  __shared__ float wmin_s[8][FPB];
  __shared__ int wcol_s[8][FPB];
  __shared__ float gmin_s[FPB];
  __shared__ int cnt_s[FPB];
  __shared__ int cand_s[FPB][32];

  const int tid = threadIdx.x;
  const int l = tid & 63;
  const int w = tid >> 6;          // 0..7
  const int ln = l & 31;
  const int lh = l >> 5;

  if (tid < FPB) rows_l[tid] = order[o0 + start + min(tid, nvalid - 1)];
  __syncthreads();

  // A staging: thread -> row (tid&63), k-slice (tid>>6)*16 floats of chunk
  const int s_row = tid & 63;
  const int s_g = tid >> 6;                      // 0..7
  const float4* emb4 = (const float4*)emb;
  const size_t arow4 = (size_t)rows_l[s_row] * (E_DIM / 4);

  float4 pa[4];
#pragma unroll
  for (int j = 0; j < 4; ++j) pa[j] = emb4[arow4 + s_g * 4 + j];
  *(bf16x8*)(A_l + ((s_g * 2 + 0) * FPB + s_row) * 8) = cvt8(pa[0], pa[1]);
  *(bf16x8*)(A_l + ((s_g * 2 + 1) * FPB + s_row) * 8) = cvt8(pa[2], pa[3]);

  // B base pointers (swizzled bf16 region in d_out); wave w -> cg {2w, 2w+1}
  const char* bbase[2];
#pragma unroll
  for (int ct = 0; ct < 2; ++ct) {
    const int cg = w * 2 + ct;
    bbase[ct] = (const char*)out + (size_t)(m * 16 + cg) * 131072 + 2048 + l * 16;
  }
#define LOADB(ct, kb) (*(const bf16x8*)(bbase[ct] + (((kb) >> 1) << 12) + (((kb) & 1) << 10)))

  bf16x8 bR[4][2];                               // depth-4 ring
#pragma unroll
  for (int d = 0; d < 4; ++d)
#pragma unroll
    for (int ct = 0; ct < 2; ++ct) bR[d][ct] = LOADB(ct, d);

  floatx16 acc[2][2] = {};

  for (int c = 0; c < NCH; ++c) {
    __syncthreads();                             // A buf (c&1) ready
    const int buf = (c & 1) * 16;
    if (c + 1 < NCH) {
#pragma unroll
      for (int j = 0; j < 4; ++j) pa[j] = emb4[arow4 + (c + 1) * 32 + s_g * 4 + j];
    }
#pragma unroll
    for (int jj = 0; jj < 8; ++jj) {
      const int kb = c * 8 + jj;
      const int p = kb & 3;
      const bf16x8 a0 = *(const bf16x8*)(A_l + ((buf + jj * 2 + lh) * FPB + ln) * 8);
      const bf16x8 a1 = *(const bf16x8*)(A_l + ((buf + jj * 2 + lh) * FPB + 32 + ln) * 8);
      acc[0][0] = __builtin_amdgcn_mfma_f32_32x32x16_bf16(a0, bR[p][0], acc[0][0], 0, 0, 0);
      acc[0][1] = __builtin_amdgcn_mfma_f32_32x32x16_bf16(a0, bR[p][1], acc[0][1], 0, 0, 0);
      acc[1][0] = __builtin_amdgcn_mfma_f32_32x32x16_bf16(a1, bR[p][0], acc[1][0], 0, 0, 0);
      acc[1][1] = __builtin_amdgcn_mfma_f32_32x32x16_bf16(a1, bR[p][1], acc[1][1], 0, 0, 0);
      if (kb + 4 < 64) {
        bR[p][0] = LOADB(0, kb + 4);
        bR[p][1] = LOADB(1, kb + 4);
      }
    }
    if (c + 1 < NCH) {                           // write other buffer
      const int nbuf = ((c + 1) & 1) * 16;
      *(bf16x8*)(A_l + ((nbuf + s_g * 2 + 0) * FPB + s_row) * 8) = cvt8(pa[0], pa[1]);
      *(bf16x8*)(A_l + ((nbuf + s_g * 2 + 1) * FPB + s_row) * 8) = cvt8(pa[2], pa[3]);
    }
  }
#undef LOADB

  // ---- per-wave argmin (scores s = csq - 2*dot stay in regs) ----
  float cs[2];
#pragma unroll
  for (int ct = 0; ct < 2; ++ct)
    cs[ct] = (float)csq64[m * K_CLUST + w * 64 + ct * 32 + ln];

#pragma unroll
  for (int rt = 0; rt < 2; ++rt) {
#pragma unroll
    for (int r = 0; r < 16; ++r) {
      const int fr = rt * 32 + (r & 3) + 8 * (r >> 2) + 4 * lh;
      float bm = cs[0] - 2.0f * acc[rt][0][r];
      int bc = w * 64 + ln;
      {
        const float s = cs[1] - 2.0f * acc[rt][1][r];
        if (s < bm) { bm = s; bc = w * 64 + 32 + ln; }
      }
#pragma unroll
      for (int sh = 1; sh <= 16; sh <<= 1) {     // reduce within lane-half
        const float om = __shfl_xor(bm, sh, 64);
        const int oc = __shfl_xor(bc, sh, 64);
        if (om < bm || (om == bm && oc < bc)) { bm = om; bc = oc; }
      }
      if (ln == 0) { wmin_s[w][fr] = bm; wcol_s[w][fr] = bc; }
    }
  }
  __syncthreads();

  for (int f0 = tid; f0 < FPB; f0 += 512) {      // cross-wave min (tid<64 does it)
    float g = wmin_s[0][f0];
    int gc = wcol_s[0][f0];
#pragma unroll
    for (int w2 = 1; w2 < 8; ++w2) {
      const float v = wmin_s[w2][f0];
      const int vc = wcol_s[w2][f0];
      if (v < g || (v == g && vc < gc)) { g = v; gc = vc; }
    }
    gmin_s[f0] = g;
    cnt_s[f0] = 0;
  }
  __syncthreads();

  // ---- candidate collection within eps = 3.0 ----
#pragma unroll
  for (int rt = 0; rt < 2; ++rt) {
#pragma unroll
    for (int r = 0; r < 16; ++r) {
      const int fr = rt * 32 + (r & 3) + 8 * (r >> 2) + 4 * lh;
      const float thr = gmin_s[fr] + 3.0f;
#pragma unroll
      for (int ct = 0; ct < 2; ++ct) {
        const float s = cs[ct] - 2.0f * acc[rt][ct][r];
        if (s < thr) {
          const int ix = atomicAdd(&cnt_s[fr], 1);
          if (ix < 32) cand_s[fr][ix] = w * 64 + ct * 32 + ln;
        }
      }
    }
  }
  __syncthreads();

  // ---- park candidate lists in out scratch: col0 = cnt, cols 1..n = ids ---
  // (cols [0,33) of any row never hold B panels; frames are block-disjoint;
  //  skip duplicated tail slots f >= nvalid to avoid torn duplicate writes)
  for (int i = 0; i < 8; ++i) {
    const int f = w * 8 + i;
    if (f >= nvalid) continue;
    const int t = rows_l[f];
    const int n = min(cnt_s[f], 32);
    if (l == 0) *(int*)(out + (size_t)t * E_DIM) = n;
    else if (l <= n) *(int*)(out + (size_t)t * E_DIM + l) = cand_s[f][l - 1];
  }
}

// ---------------- K4: resolve candidates -> output rows (all frames) -------
// One wave per frame. n==1: straight row copy. n>1: exact fp64 recheck over
// the candidate list (reads emb row + cand cent rows), then row copy.
__global__ __launch_bounds__(256) void k_resolve(const float* __restrict__ emb,
                                                 const float* __restrict__ cent,
                                                 const double* __restrict__ csq64,
                                                 const int* __restrict__ midx,
                                                 float* __restrict__ out) {
  const int t = blockIdx.x * 4 + (threadIdx.x >> 6);
  const int l = threadIdx.x & 63;
  const int m = midx[t];
  float* drow = out + (size_t)t * E_DIM;
  const int n = *(const int*)drow;
  int code;
  if (n == 1) {
    code = *(const int*)(drow + 1);
  } else {
    const float4* emb4 = (const float4*)emb;
    float4 xv[4];
#pragma unroll
    for (int q = 0; q < 4; ++q) xv[q] = emb4[(size_t)t * (E_DIM / 4) + q * 64 + l];
    double bd = 1e300;
    int bi = 1 << 30;
    for (int j = 0; j < n; ++j) {
      const int cc = *(const int*)(drow + 1 + j);
      const float4* crow4 = (const float4*)(cent + ((size_t)(m * K_CLUST + cc)) * E_DIM);
      double s = 0.0;
#pragma unroll
      for (int q = 0; q < 4; ++q) {
        const float4 cv = crow4[q * 64 + l];
        s += (double)xv[q].x * cv.x + (double)xv[q].y * cv.y +
             (double)xv[q].z * cv.z + (double)xv[q].w * cv.w;
      }
#pragma unroll
      for (int sh = 32; sh >= 1; sh >>= 1) s += __shfl_xor(s, sh, 64);
      const double d = csq64[m * K_CLUST + cc] - 2.0 * s;
      if (d < bd || (d == bd && cc < bi)) { bd = d; bi = cc; }
    }
    code = bi;
  }
  const float4* src = (const float4*)(cent + ((size_t)(m * K_CLUST + code)) * E_DIM);
  float4* dst = (float4*)drow;
#pragma unroll
  for (int q = 0; q < 4; ++q) dst[q * 64 + l] = src[q * 64 + l];
}

extern "C" void kernel_launch(void* const* d_in, const int* in_sizes, int n_in,
                              void* d_out, int out_size, void* d_ws, size_t ws_size,
                              hipStream_t stream) {
  const float* emb = (const float*)d_in[0];     // [1,T,E] fp32
  const float* cent = (const float*)d_in[1];    // [M,K,E] fp32
  const int* midx = (const int*)d_in[2];        // [T] int32
  float* out = (float*)d_out;                   // [1,T,E] fp32

  char* ws = (char*)d_ws;                       // ~100 KB
  double* csq64 = (double*)(ws + 0);
  int* hist = (int*)(ws + 32768);
  int* offs = (int*)(ws + 34816);
  int* order = (int*)(ws + 34880);

  hipLaunchKernelGGL(k_hist, dim3(64), dim3(256), 0, stream, midx, hist, csq64);
  hipLaunchKernelGGL(k_scatter, dim3(64), dim3(256), 0, stream, midx, hist, order, offs);
  hipLaunchKernelGGL(k_cvt, dim3(512), dim3(256), 0, stream, cent, out, csq64);
  hipLaunchKernelGGL(k_dist, dim3(M_MODELS, 40), dim3(512), 0, stream,
                     emb, cent, csq64, order, offs, out);
  hipLaunchKernelGGL(k_resolve, dim3(T_FRAMES / 4), dim3(256), 0, stream,
                     emb, cent, csq64, midx, out);
}

// Round 6
// 196.399 us; speedup vs baseline: 1.0696x; 1.0696x over previous
//
#include <hip/hip_runtime.h>

// MultipleKmeans: T=16384 frames, E=1024, M=8 models, K=512 clusters.
// Round 10: RESUBMISSION of R9 unchanged (container failed twice before
// any measurement; no kernel defect found on audit).
// R9 changes on top of R7 (best total, 202.4):
//  1. k_dist B-ring depth 4 -> 8 (16 outstanding loads/wave). R4-R8
//     invariance plus per-step cycle arithmetic (~1500-3000 cyc/step)
//     points at per-wave B latency (L3, not L2: the A stream blows the
//     4MB XCD L2) with stall ~= latency/depth. Depth was the one never-
//     varied knob. launch_bounds(512,2) to hold VGPR without spill.
//  2. k_hist fused into k_cvt (blocks 0..63 also histogram their midx
//     segment); csq64 zeroed by one hipMemsetAsync node. One less launch.
// Pipeline: memset(csq) -> cvt(+hist) -> scatter -> dist -> gather(1/4).
//
// ws layout (<=100416 B):
//   [     0, 32768): double csq64[M*K]
//   [ 32768, 34816): int    hist[64][8]
//   [ 34816, 34880): int    offs[9]
//   [ 34880,100416): int    order[T]

#define T_FRAMES 16384
#define E_DIM    1024
#define M_MODELS 8
#define K_CLUST  512

#define FPB 32     // frames per k_dist block
#define NCH 8      // K chunks of 128

typedef __bf16 bf16x8 __attribute__((ext_vector_type(8)));
typedef float  floatx16 __attribute__((ext_vector_type(16)));

__device__ __forceinline__ bf16x8 cvt8(const float4 a, const float4 b) {
  bf16x8 h;
  h[0] = (__bf16)a.x; h[1] = (__bf16)a.y; h[2] = (__bf16)a.z; h[3] = (__bf16)a.w;
  h[4] = (__bf16)b.x; h[5] = (__bf16)b.y; h[6] = (__bf16)b.z; h[7] = (__bf16)b.w;
  return h;
}

// ------- K0: cent fp32 -> swizzled bf16 (+csq64) + hist (blocks 0..63) -----
__global__ __launch_bounds__(256) void k_cvt(const float* __restrict__ cent,
                                             float* __restrict__ out,
                                             double* __restrict__ csq64,
                                             const int* __restrict__ midx,
                                             int* __restrict__ hist) {
  const int b = blockIdx.x;              // 512 blocks
  const int m = b >> 6;
  const int cg = (b >> 2) & 15;
  const int q = b & 3;
  const int tid = threadIdx.x;
  const int ci = tid & 31;
  const int t8 = tid >> 5;               // 0..7
  const int gk0 = q * 32 + t8 * 4;
  const int B32 = (m * 16 + cg) * 32;
  const float* src = cent + ((size_t)(m * K_CLUST + cg * 32 + ci)) * E_DIM;
  double ss = 0.0;
#pragma unroll
  for (int j = 0; j < 4; ++j) {
    const int gk = gk0 + j;
    const float4 a = *(const float4*)(src + gk * 8);
    const float4 bb = *(const float4*)(src + gk * 8 + 4);
    ss += (double)a.x * a.x + (double)a.y * a.y + (double)a.z * a.z +
          (double)a.w * a.w + (double)bb.x * bb.x + (double)bb.y * bb.y +
          (double)bb.z * bb.z + (double)bb.w * bb.w;
    const size_t foff = (size_t)(B32 + (gk >> 2)) * 1024 + 512 +
                        ((gk & 3) * 32 + ci) * 4;
    *(bf16x8*)(out + foff) = cvt8(a, bb);
  }
  __shared__ double csq_l[32][8];
  csq_l[ci][t8] = ss;
  __syncthreads();
  if (tid < 32) {
    double s = 0.0;
#pragma unroll
    for (int t = 0; t < 8; ++t) s += csq_l[tid][t];
    atomicAdd(&csq64[m * K_CLUST + cg * 32 + tid], s);
  }
  // ---- fused per-segment model histogram (blocks 0..63 only) ----
  if (b < 64) {
    __shared__ int h[M_MODELS * 33];
    for (int i = tid; i < M_MODELS * 33; i += 256) h[i] = 0;
    __syncthreads();
    const int mm = midx[b * 256 + tid];
    atomicAdd(&h[mm * 33 + (tid & 31)], 1);
    __syncthreads();
    if (tid < M_MODELS) {
      int s = 0;
      for (int j = 0; j < 32; ++j) s += h[tid * 33 + j];
      hist[b * M_MODELS + tid] = s;
    }
  }
}

// ---------------- K2: scatter frames into per-model buckets ----------------
__global__ __launch_bounds__(256) void k_scatter(const int* __restrict__ midx,
                                                 const int* __restrict__ hist,
                                                 int* __restrict__ order,
                                                 int* __restrict__ offs) {
  __shared__ int h2[64 * M_MODELS];
  __shared__ int cur[M_MODELS];
  const int tid = threadIdx.x;
  h2[tid] = hist[tid];
  h2[tid + 256] = hist[tid + 256];
  __syncthreads();
  if (tid < M_MODELS) {
    int tot_before = 0;
    for (int mp = 0; mp < tid; ++mp)
      for (int b = 0; b < 64; ++b) tot_before += h2[b * M_MODELS + mp];
    int prior = 0;
    for (int b = 0; b < (int)blockIdx.x; ++b) prior += h2[b * M_MODELS + tid];
    cur[tid] = tot_before + prior;
  }
  if (blockIdx.x == 0 && tid <= M_MODELS) {
    int o = 0;
    for (int mp = 0; mp < tid; ++mp)
      for (int b = 0; b < 64; ++b) o += h2[b * M_MODELS + mp];
    offs[tid] = o;
  }
  __syncthreads();
  const int f = blockIdx.x * 256 + tid;
  const int pos = atomicAdd(&cur[midx[f]], 1);
  order[pos] = f;
}

// ---------------- K3: fused scores + argmin + recheck -> code/output -------
// Block: 8 waves (512 thr), tile = 32 frames x 512 cols; wave w -> cols
// [w*64, w*64+64). acc: 2 x 32x32 tiles = 32 regs/wave. A: LDS chunks of
// 128 k, double-buffered (16 KB). B: swizzled bf16 (d_out rows 0..4095
// high halves), DEPTH-8 register ring (16 outstanding loads/wave).
// grid = (M, 80): linear id % 8 == m -> per-model XCD affinity.
// Resolution: t>=4096 -> direct row write; t<4096 -> park code at col 0.
__global__ __launch_bounds__(512, 2) void k_dist(const float* __restrict__ emb,
                                                 const float* __restrict__ cent,
                                                 const double* __restrict__ csq64,
                                                 const int* __restrict__ order,
                                                 const int* __restrict__ offs,
                                                 float* __restrict__ out) {
  const int m = blockIdx.x;
  const int o0 = offs[m];
  const int cnt = offs[m + 1] - o0;
  const int start = blockIdx.y * FPB;
  if (start >= cnt) return;
  const int nvalid = min(FPB, cnt - start);

  __shared__ __align__(16) __bf16 A_l[2 * 16 * FPB * 8];  // 16 KB
  __shared__ int rows_l[FPB];
  __shared__ float wmin_s[8][FPB];
  __shared__ int wcol_s[8][FPB];
  __shared__ float gmin_s[FPB];
  __shared__ int cnt_s[FPB];
  __shared__ int cand_s[FPB][32];

  const int tid = threadIdx.x;
  const int l = tid & 63;
  const int w = tid >> 6;          // 0..7
  const int ln = l & 31;
  const int lh = l >> 5;

  if (tid < FPB) rows_l[tid] = order[o0 + start + min(tid, nvalid - 1)];
  __syncthreads();

  // A staging role: thread -> row (tid&31), k-granule (tid>>5), 1 granule each
  const int s_row = tid & 31;
  const int s_g = tid >> 5;                      // 0..15
  const float4* emb4 = (const float4*)emb;
  const size_t arow4 = (size_t)rows_l[s_row] * (E_DIM / 4);

  float4 pa[2];
  pa[0] = emb4[arow4 + s_g * 2 + 0];
  pa[1] = emb4[arow4 + s_g * 2 + 1];
  *(bf16x8*)(A_l + ((s_g)*FPB + s_row) * 8) = cvt8(pa[0], pa[1]);

  // B base pointers (swizzled bf16 region in d_out); wave w -> cg {2w, 2w+1}
  const char* bbase[2];
#pragma unroll
  for (int ct = 0; ct < 2; ++ct) {
    const int cg = w * 2 + ct;
    bbase[ct] = (const char*)out + (size_t)(m * 16 + cg) * 131072 + 2048 + l * 16;
  }
#define LOADB(ct, kb) (*(const bf16x8*)(bbase[ct] + (((kb) >> 1) << 12) + (((kb) & 1) << 10)))

  bf16x8 bR[8][2];                               // depth-8 ring
#pragma unroll
  for (int d = 0; d < 8; ++d)
#pragma unroll
    for (int ct = 0; ct < 2; ++ct) bR[d][ct] = LOADB(ct, d);

  floatx16 acc[2] = {};

  for (int c = 0; c < NCH; ++c) {
    __syncthreads();                             // A buf (c&1) ready
    const int buf = (c & 1) * 16;
    if (c + 1 < NCH) {
      pa[0] = emb4[arow4 + (c + 1) * 32 + s_g * 2 + 0];
      pa[1] = emb4[arow4 + (c + 1) * 32 + s_g * 2 + 1];
    }
#pragma unroll
    for (int jj = 0; jj < 8; ++jj) {
      const int kb = c * 8 + jj;
      const int p = kb & 7;
      const bf16x8 a0 = *(const bf16x8*)(A_l + ((buf + jj * 2 + lh) * FPB + ln) * 8);
      acc[0] = __builtin_amdgcn_mfma_f32_32x32x16_bf16(a0, bR[p][0], acc[0], 0, 0, 0);
      acc[1] = __builtin_amdgcn_mfma_f32_32x32x16_bf16(a0, bR[p][1], acc[1], 0, 0, 0);
      if (kb + 8 < 64) {
        bR[p][0] = LOADB(0, kb + 8);
        bR[p][1] = LOADB(1, kb + 8);
      }
    }
    if (c + 1 < NCH) {                           // write other buffer
      const int nbuf = ((c + 1) & 1) * 16;
      *(bf16x8*)(A_l + ((nbuf + s_g) * FPB + s_row) * 8) = cvt8(pa[0], pa[1]);
    }
  }
#undef LOADB

  // ---- per-wave argmin (scores s = csq - 2*dot stay in regs) ----
  float cs[2];
#pragma unroll
  for (int ct = 0; ct < 2; ++ct)
    cs[ct] = (float)csq64[m * K_CLUST + w * 64 + ct * 32 + ln];

#pragma unroll
  for (int r = 0; r < 16; ++r) {
    const int fr = (r & 3) + 8 * (r >> 2) + 4 * lh;
    float bm = cs[0] - 2.0f * acc[0][r];
    int bc = w * 64 + ln;
    {
      const float s = cs[1] - 2.0f * acc[1][r];
      if (s < bm) { bm = s; bc = w * 64 + 32 + ln; }
    }
#pragma unroll
    for (int sh = 1; sh <= 16; sh <<= 1) {       // reduce within lane-half
      const float om = __shfl_xor(bm, sh, 64);
      const int oc = __shfl_xor(bc, sh, 64);
      if (om < bm || (om == bm && oc < bc)) { bm = om; bc = oc; }
    }
    if (ln == 0) { wmin_s[w][fr] = bm; wcol_s[w][fr] = bc; }
  }
  __syncthreads();

  if (tid < FPB) {                               // cross-wave min
    float g = wmin_s[0][tid];
    int gc = wcol_s[0][tid];
#pragma unroll
    for (int w2 = 1; w2 < 8; ++w2) {
      const float v = wmin_s[w2][tid];
      const int vc = wcol_s[w2][tid];
      if (v < g || (v == g && vc < gc)) { g = v; gc = vc; }
    }
    gmin_s[tid] = g;
    cnt_s[tid] = 0;
  }
  __syncthreads();

  // ---- candidate collection within eps = 3.0 ----
#pragma unroll
  for (int r = 0; r < 16; ++r) {
    const int fr = (r & 3) + 8 * (r >> 2) + 4 * lh;
    const float thr = gmin_s[fr] + 3.0f;
#pragma unroll
    for (int ct = 0; ct < 2; ++ct) {
      const float s = cs[ct] - 2.0f * acc[ct][r];
      if (s < thr) {
        const int ix = atomicAdd(&cnt_s[fr], 1);
        if (ix < 32) cand_s[fr][ix] = w * 64 + ct * 32 + ln;
      }
    }
  }
  __syncthreads();

  // ---- resolution: wave w -> frames w*4 .. w*4+3; exact fp64 recheck ----
  for (int i = 0; i < 4; ++i) {
    const int f = w * 4 + i;
    const int t = rows_l[f];
    const int n = min(cnt_s[f], 32);
    int code;
    if (n == 1) {
      code = cand_s[f][0];
    } else {
      float4 xv[4];
#pragma unroll
      for (int q = 0; q < 4; ++q) xv[q] = emb4[(size_t)t * (E_DIM / 4) + q * 64 + l];
      double bd = 1e300;
      int bi = 1 << 30;
      for (int j = 0; j < n; ++j) {
        const int cc = cand_s[f][j];
        const float4* crow4 = (const float4*)(cent + ((size_t)(m * K_CLUST + cc)) * E_DIM);
        double s = 0.0;
#pragma unroll
        for (int q = 0; q < 4; ++q) {
          const float4 cv = crow4[q * 64 + l];
          s += (double)xv[q].x * cv.x + (double)xv[q].y * cv.y +
               (double)xv[q].z * cv.z + (double)xv[q].w * cv.w;
        }
#pragma unroll
        for (int sh = 32; sh >= 1; sh >>= 1) s += __shfl_xor(s, sh, 64);
        const double d = csq64[m * K_CLUST + cc] - 2.0 * s;
        if (d < bd || (d == bd && cc < bi)) { bd = d; bi = cc; }
      }
      code = bi;
    }
    if (t >= 4096) {
      // rows >= 4096 never hold B panels: write the output row directly.
      const float4* crow = (const float4*)(cent + ((size_t)(m * K_CLUST + code)) * E_DIM);
      float4* drow = (float4*)(out + (size_t)t * E_DIM);
#pragma unroll
      for (int q = 0; q < 4; ++q) drow[q * 64 + l] = crow[q * 64 + l];
    } else if (l == 0) {
      *(int*)(out + (size_t)t * E_DIM) = code;   // col 0: no B overlap
    }
  }
}

// ---------------- K4: expand parked codes (t < 4096) -> output rows --------
__global__ __launch_bounds__(256) void k_gather(const float* __restrict__ cent,
                                                const int* __restrict__ midx,
                                                float* __restrict__ out) {
  const int t = blockIdx.x * 4 + (threadIdx.x >> 6);   // t in [0, 4096)
  const int l = threadIdx.x & 63;
  float* drow = out + (size_t)t * E_DIM;
  const int code = *(const int*)drow;            // read before overwrite (dep-ordered)
  const int m = midx[t];
  const float4* src = (const float4*)(cent + ((size_t)(m * K_CLUST + code)) * E_DIM);
  float4* dst = (float4*)drow;
#pragma unroll
  for (int q = 0; q < 4; ++q) dst[q * 64 + l] = src[q * 64 + l];
}

extern "C" void kernel_launch(void* const* d_in, const int* in_sizes, int n_in,
                              void* d_out, int out_size, void* d_ws, size_t ws_size,
                              hipStream_t stream) {
  const float* emb = (const float*)d_in[0];     // [1,T,E] fp32
  const float* cent = (const float*)d_in[1];    // [M,K,E] fp32
  const int* midx = (const int*)d_in[2];        // [T] int32
  float* out = (float*)d_out;                   // [1,T,E] fp32

  char* ws = (char*)d_ws;                       // ~100 KB
  double* csq64 = (double*)(ws + 0);
  int* hist = (int*)(ws + 32768);
  int* offs = (int*)(ws + 34816);
  int* order = (int*)(ws + 34880);

  hipMemsetAsync(csq64, 0, M_MODELS * K_CLUST * sizeof(double), stream);
  hipLaunchKernelGGL(k_cvt, dim3(512), dim3(256), 0, stream,
                     cent, out, csq64, midx, hist);
  hipLaunchKernelGGL(k_scatter, dim3(64), dim3(256), 0, stream, midx, hist, order, offs);
  hipLaunchKernelGGL(k_dist, dim3(M_MODELS, 80), dim3(512), 0, stream,
                     emb, cent, csq64, order, offs, out);
  hipLaunchKernelGGL(k_gather, dim3(4096 / 4), dim3(256), 0, stream,
                     cent, midx, out);
}